// Round 2
// baseline (1476.037 us; speedup 1.0000x reference)
//
#include <hip/hip_runtime.h>
#include <math.h>

#define NH   16
#define HD   64
#define HIDN 1024
#define NB   2
#define SEQ  2048
#define ROWS (NB*SEQ)   // 4096

// score = (1 + acos(clip(c)))^-65
__device__ __forceinline__ float score_fn(float c) {
    c = fminf(fmaxf(c, -1.0f + 1e-7f), 1.0f - 1e-7f);
    float g = acosf(c);
    return exp2f(-65.0f * log2f(1.0f + g));
}

// ---------------- fp32 NT GEMM: C[M,N] = A[M,K] * B[N,K]^T + bias[N] ---------
// tile 128x128, K-chunk 16, 256 threads, 8x8 micro-tile per thread
__global__ __launch_bounds__(256)
void gemm_nt_f32(const float* __restrict__ A, const float* __restrict__ Bm,
                 const float* __restrict__ bias, float* __restrict__ C,
                 int M, int N, int K)
{
    __shared__ float As[16][132];
    __shared__ float Bs[16][132];
    const int tid = threadIdx.x;
    const int tx = tid & 15, ty = tid >> 4;
    const int m0 = blockIdx.x * 128, n0 = blockIdx.y * 128;

    float acc[8][8];
    #pragma unroll
    for (int i = 0; i < 8; ++i)
        #pragma unroll
        for (int j = 0; j < 8; ++j) acc[i][j] = 0.f;

    const int lrow0 = tid >> 2;        // 0..63
    const int lk    = (tid & 3) * 4;   // 0,4,8,12

    for (int kc = 0; kc < K; kc += 16) {
        #pragma unroll
        for (int l = 0; l < 2; ++l) {
            int row = lrow0 + l * 64;
            float4 av = *(const float4*)&A[(size_t)(m0 + row) * K + kc + lk];
            float4 bv = *(const float4*)&Bm[(size_t)(n0 + row) * K + kc + lk];
            As[lk+0][row] = av.x; As[lk+1][row] = av.y;
            As[lk+2][row] = av.z; As[lk+3][row] = av.w;
            Bs[lk+0][row] = bv.x; Bs[lk+1][row] = bv.y;
            Bs[lk+2][row] = bv.z; Bs[lk+3][row] = bv.w;
        }
        __syncthreads();
        #pragma unroll
        for (int k = 0; k < 16; ++k) {
            float4 a0 = *(const float4*)&As[k][ty*8];
            float4 a1 = *(const float4*)&As[k][ty*8+4];
            float4 b0 = *(const float4*)&Bs[k][tx*8];
            float4 b1 = *(const float4*)&Bs[k][tx*8+4];
            float a[8] = {a0.x,a0.y,a0.z,a0.w,a1.x,a1.y,a1.z,a1.w};
            float b[8] = {b0.x,b0.y,b0.z,b0.w,b1.x,b1.y,b1.z,b1.w};
            #pragma unroll
            for (int i = 0; i < 8; ++i)
                #pragma unroll
                for (int j = 0; j < 8; ++j)
                    acc[i][j] = fmaf(a[i], b[j], acc[i][j]);
        }
        __syncthreads();
    }

    float bsr[8];
    #pragma unroll
    for (int j = 0; j < 8; ++j) bsr[j] = bias[n0 + tx*8 + j];
    #pragma unroll
    for (int i = 0; i < 8; ++i) {
        size_t r = (size_t)(m0 + ty*8 + i) * N + n0 + tx*8;
        float4 o0 = make_float4(acc[i][0]+bsr[0], acc[i][1]+bsr[1],
                                acc[i][2]+bsr[2], acc[i][3]+bsr[3]);
        float4 o1 = make_float4(acc[i][4]+bsr[4], acc[i][5]+bsr[5],
                                acc[i][6]+bsr[6], acc[i][7]+bsr[7]);
        *(float4*)&C[r]     = o0;
        *(float4*)&C[r + 4] = o1;
    }
}

// ------------- normalize q,k and transpose to [B,H,S,D]; copy v -------------
__global__ __launch_bounds__(256)
void normalize_qkv(const float* __restrict__ qkv, float* __restrict__ qn,
                   float* __restrict__ kn, float* __restrict__ vv)
{
    int w    = blockIdx.x * 4 + (threadIdx.x >> 6);  // 0..65535  (row,head)
    int lane = threadIdx.x & 63;
    int n = w >> 4;          // row in [0,4096)
    int h = w & 15;
    int b = n >> 11;
    int s = n & 2047;
    const float* base = qkv + (size_t)n * 3 * HIDN + h * HD;
    float q = base[lane];
    float k = base[HIDN + lane];
    float v = base[2 * HIDN + lane];
    float qs = q * q, ks = k * k;
    #pragma unroll
    for (int o = 32; o; o >>= 1) {
        qs += __shfl_xor(qs, o);
        ks += __shfl_xor(ks, o);
    }
    float qr = 1.0f / fmaxf(sqrtf(qs), 1e-12f);
    float kr = 1.0f / fmaxf(sqrtf(ks), 1e-12f);
    size_t idx = ((size_t)((b * NH + h) * SEQ + s)) * HD + lane;
    qn[idx] = q * qr;
    kn[idx] = k * kr;
    vv[idx] = v;
}

// ------------- column sums: col[bh,t] = (sum_s score(q_s . k_t))^-0.5 -------
__global__ __launch_bounds__(256)
void col_sum_kernel(const float* __restrict__ qn, const float* __restrict__ kn,
                    float* __restrict__ col)
{
    __shared__ float Qs[64][68];
    __shared__ float Ks[64][68];
    __shared__ float red[16][64];
    const int bh = blockIdx.x;        // 0..31
    const int t0 = blockIdx.y * 64;   // t-tile
    const int tid = threadIdx.x;
    const int tx = tid & 15, ty = tid >> 4;
    const float* qb = qn + (size_t)bh * SEQ * HD;
    const float* kb = kn + (size_t)bh * SEQ * HD;

    {   // stage K tile (persistent)
        int row = tid >> 2;
        int c0  = (tid & 3) * 16;
        const float4* src = (const float4*)&kb[(size_t)(t0 + row) * HD + c0];
        float4 v0 = src[0], v1 = src[1], v2 = src[2], v3 = src[3];
        *(float4*)&Ks[row][c0+0]  = v0;
        *(float4*)&Ks[row][c0+4]  = v1;
        *(float4*)&Ks[row][c0+8]  = v2;
        *(float4*)&Ks[row][c0+12] = v3;
    }

    float cacc[4] = {0.f, 0.f, 0.f, 0.f};
    for (int st = 0; st < SEQ / 64; ++st) {
        __syncthreads();
        {   // stage Q tile
            int row = tid >> 2;
            int c0  = (tid & 3) * 16;
            const float4* src = (const float4*)&qb[(size_t)(st * 64 + row) * HD + c0];
            float4 v0 = src[0], v1 = src[1], v2 = src[2], v3 = src[3];
            *(float4*)&Qs[row][c0+0]  = v0;
            *(float4*)&Qs[row][c0+4]  = v1;
            *(float4*)&Qs[row][c0+8]  = v2;
            *(float4*)&Qs[row][c0+12] = v3;
        }
        __syncthreads();
        float acc[4][4];
        #pragma unroll
        for (int i = 0; i < 4; ++i)
            #pragma unroll
            for (int j = 0; j < 4; ++j) acc[i][j] = 0.f;
        for (int kk = 0; kk < HD; kk += 4) {
            float4 qa[4], ka[4];
            #pragma unroll
            for (int i = 0; i < 4; ++i) qa[i] = *(const float4*)&Qs[ty + i*16][kk];
            #pragma unroll
            for (int j = 0; j < 4; ++j) ka[j] = *(const float4*)&Ks[tx + j*16][kk];
            #pragma unroll
            for (int i = 0; i < 4; ++i)
                #pragma unroll
                for (int j = 0; j < 4; ++j) {
                    acc[i][j] = fmaf(qa[i].x, ka[j].x, acc[i][j]);
                    acc[i][j] = fmaf(qa[i].y, ka[j].y, acc[i][j]);
                    acc[i][j] = fmaf(qa[i].z, ka[j].z, acc[i][j]);
                    acc[i][j] = fmaf(qa[i].w, ka[j].w, acc[i][j]);
                }
        }
        #pragma unroll
        for (int i = 0; i < 4; ++i)
            #pragma unroll
            for (int j = 0; j < 4; ++j) cacc[j] += score_fn(acc[i][j]);
    }

    #pragma unroll
    for (int j = 0; j < 4; ++j) red[ty][tx + j*16] = cacc[j];
    __syncthreads();
    if (tid < 64) {
        float s = 0.f;
        #pragma unroll
        for (int r = 0; r < 16; ++r) s += red[r][tid];
        col[(size_t)bh * SEQ + t0 + tid] = 1.0f / sqrtf(s);   // ^(-0.5)
    }
}

// ------------- fused probs @ V with on-the-fly score recompute --------------
__global__ __launch_bounds__(256)
void attn_out_kernel(const float* __restrict__ qn, const float* __restrict__ kn,
                     const float* __restrict__ vv, const float* __restrict__ col,
                     float* __restrict__ ctx)
{
    __shared__ float Qs[64][68];
    __shared__ float Ks[64][68];
    __shared__ float VsT[64][68];
    __shared__ float Ws[64][68];
    __shared__ float cl[64];
    __shared__ float denom[64];
    const int bh = blockIdx.x;        // 0..31
    const int s0 = blockIdx.y * 64;   // s-tile
    const int b = bh >> 4, h = bh & 15;
    const int tid = threadIdx.x;
    const int tx = tid & 15, ty = tid >> 4;
    const float* qb = qn + (size_t)bh * SEQ * HD;
    const float* kb = kn + (size_t)bh * SEQ * HD;
    const float* vb = vv + (size_t)bh * SEQ * HD;

    {   // stage Q tile (persistent)
        int row = tid >> 2;
        int c0  = (tid & 3) * 16;
        const float4* src = (const float4*)&qb[(size_t)(s0 + row) * HD + c0];
        float4 v0 = src[0], v1 = src[1], v2 = src[2], v3 = src[3];
        *(float4*)&Qs[row][c0+0]  = v0;
        *(float4*)&Qs[row][c0+4]  = v1;
        *(float4*)&Qs[row][c0+8]  = v2;
        *(float4*)&Qs[row][c0+12] = v3;
    }
    if (tid < 64) denom[tid] = 0.f;

    float num[4][4];
    #pragma unroll
    for (int i = 0; i < 4; ++i)
        #pragma unroll
        for (int j = 0; j < 4; ++j) num[i][j] = 0.f;
    float dpart[4] = {0.f, 0.f, 0.f, 0.f};

    for (int tt = 0; tt < SEQ / 64; ++tt) {
        int t0 = tt * 64;
        __syncthreads();
        {   // stage K tile and V^T tile
            int row = tid >> 2;
            int c0  = (tid & 3) * 16;
            const float4* ksrc = (const float4*)&kb[(size_t)(t0 + row) * HD + c0];
            float4 k0 = ksrc[0], k1 = ksrc[1], k2 = ksrc[2], k3 = ksrc[3];
            *(float4*)&Ks[row][c0+0]  = k0;
            *(float4*)&Ks[row][c0+4]  = k1;
            *(float4*)&Ks[row][c0+8]  = k2;
            *(float4*)&Ks[row][c0+12] = k3;
            const float4* vsrc = (const float4*)&vb[(size_t)(t0 + row) * HD + c0];
            float4 w0 = vsrc[0], w1 = vsrc[1], w2 = vsrc[2], w3 = vsrc[3];
            float tmp[16] = {w0.x,w0.y,w0.z,w0.w, w1.x,w1.y,w1.z,w1.w,
                             w2.x,w2.y,w2.z,w2.w, w3.x,w3.y,w3.z,w3.w};
            #pragma unroll
            for (int q = 0; q < 16; ++q) VsT[c0 + q][row] = tmp[q];
            if (tid < 64) cl[tid] = col[(size_t)bh * SEQ + t0 + tid];
        }
        __syncthreads();

        // phase A: scores
        float acc[4][4];
        #pragma unroll
        for (int i = 0; i < 4; ++i)
            #pragma unroll
            for (int j = 0; j < 4; ++j) acc[i][j] = 0.f;
        for (int kk = 0; kk < HD; kk += 4) {
            float4 qa[4], ka[4];
            #pragma unroll
            for (int i = 0; i < 4; ++i) qa[i] = *(const float4*)&Qs[ty + i*16][kk];
            #pragma unroll
            for (int j = 0; j < 4; ++j) ka[j] = *(const float4*)&Ks[tx + j*16][kk];
            #pragma unroll
            for (int i = 0; i < 4; ++i)
                #pragma unroll
                for (int j = 0; j < 4; ++j) {
                    acc[i][j] = fmaf(qa[i].x, ka[j].x, acc[i][j]);
                    acc[i][j] = fmaf(qa[i].y, ka[j].y, acc[i][j]);
                    acc[i][j] = fmaf(qa[i].z, ka[j].z, acc[i][j]);
                    acc[i][j] = fmaf(qa[i].w, ka[j].w, acc[i][j]);
                }
        }
        #pragma unroll
        for (int i = 0; i < 4; ++i)
            #pragma unroll
            for (int j = 0; j < 4; ++j) {
                float w = score_fn(acc[i][j]) * cl[tx + j*16];
                dpart[i] += w;
                Ws[ty + i*16][tx + j*16] = w;
            }
        __syncthreads();

        // phase B: num += W @ V
        for (int t4 = 0; t4 < 64; t4 += 4) {
            float4 wv[4], vvv[4];
            #pragma unroll
            for (int i = 0; i < 4; ++i) wv[i]  = *(const float4*)&Ws[ty + i*16][t4];
            #pragma unroll
            for (int j = 0; j < 4; ++j) vvv[j] = *(const float4*)&VsT[tx + j*16][t4];
            #pragma unroll
            for (int i = 0; i < 4; ++i)
                #pragma unroll
                for (int j = 0; j < 4; ++j) {
                    num[i][j] = fmaf(wv[i].x, vvv[j].x, num[i][j]);
                    num[i][j] = fmaf(wv[i].y, vvv[j].y, num[i][j]);
                    num[i][j] = fmaf(wv[i].z, vvv[j].z, num[i][j]);
                    num[i][j] = fmaf(wv[i].w, vvv[j].w, num[i][j]);
                }
        }
    }

    #pragma unroll
    for (int i = 0; i < 4; ++i) atomicAdd(&denom[ty + i*16], dpart[i]);
    __syncthreads();

    #pragma unroll
    for (int i = 0; i < 4; ++i) {
        float dn = fmaxf(denom[ty + i*16], 1e-12f);
        float inv = 1.0f / dn;
        #pragma unroll
        for (int j = 0; j < 4; ++j) {
            ctx[((size_t)(b * SEQ + s0 + ty + i*16)) * HIDN + h * HD + tx + j*16] =
                num[i][j] * inv;
        }
    }
}

extern "C" void kernel_launch(void* const* d_in, const int* in_sizes, int n_in,
                              void* d_out, int out_size, void* d_ws, size_t ws_size,
                              hipStream_t stream) {
    const float* x      = (const float*)d_in[0];   // [2,2048,1024]
    const float* qkv_w  = (const float*)d_in[1];   // [3072,1024]
    const float* qkv_b  = (const float*)d_in[2];   // [3072]
    const float* out_w  = (const float*)d_in[3];   // [1024,1024]
    const float* out_b  = (const float*)d_in[4];   // [1024]
    float* out = (float*)d_out;                    // [2,2048,1024]

    float* qkv = (float*)d_ws;                            // 4096*3072
    float* qn  = qkv + (size_t)ROWS * 3 * HIDN;           // [B,H,S,D]
    float* kn  = qn  + (size_t)NB * NH * SEQ * HD;
    float* vvp = kn  + (size_t)NB * NH * SEQ * HD;
    float* ctx = vvp + (size_t)NB * NH * SEQ * HD;        // [B,S,HID]
    float* col = ctx + (size_t)ROWS * HIDN;               // [B*H,S]

    // 1. QKV projection
    gemm_nt_f32<<<dim3(ROWS/128, 3*HIDN/128), 256, 0, stream>>>(
        x, qkv_w, qkv_b, qkv, ROWS, 3*HIDN, HIDN);
    // 2. normalize + transpose
    normalize_qkv<<<ROWS*NH/4, 256, 0, stream>>>(qkv, qn, kn, vvp);
    // 3. column sums -> col^-0.5
    col_sum_kernel<<<dim3(NB*NH, SEQ/64), 256, 0, stream>>>(qn, kn, col);
    // 4. fused scores + probs @ V
    attn_out_kernel<<<dim3(NB*NH, SEQ/64), 256, 0, stream>>>(qn, kn, vvp, col, ctx);
    // 5. output projection
    gemm_nt_f32<<<dim3(ROWS/128, HIDN/128), 256, 0, stream>>>(
        ctx, out_w, out_b, out, ROWS, HIDN, HIDN);
}

// Round 3
// 1208.144 us; speedup vs baseline: 1.2217x; 1.2217x over previous
//
#include <hip/hip_runtime.h>
#include <math.h>

#define NH   16
#define HD   64
#define HIDN 1024
#define NB   2
#define SEQ  2048
#define ROWS (NB*SEQ)   // 4096
#define BH   (NB*NH)    // 32

typedef __attribute__((ext_vector_type(8))) short bf16x8;
typedef __attribute__((ext_vector_type(4))) float f32x4;

__device__ __forceinline__ unsigned short f2bf(float f) {
    unsigned u = __float_as_uint(f);
    u += 0x7FFF + ((u >> 16) & 1);          // RNE
    return (unsigned short)(u >> 16);
}
__device__ __forceinline__ float bf2f(unsigned short h) {
    return __uint_as_float(((unsigned)h) << 16);
}
__device__ __forceinline__ bf16x8 ldfrag(const unsigned short* p) {
    return *(const bf16x8*)p;
}
__device__ __forceinline__ f32x4 mfma16(bf16x8 a, bf16x8 b, f32x4 c) {
    return __builtin_amdgcn_mfma_f32_16x16x32_bf16(a, b, c, 0, 0, 0);
}

// score = (1 + acos(clip(c)))^-65
__device__ __forceinline__ float score_fn(float c) {
    c = fminf(fmaxf(c, -1.0f + 1e-7f), 1.0f - 1e-7f);
    float g = acosf(c);
    return exp2f(-65.0f * log2f(1.0f + g));
}

// ---------------- fp32 NT GEMM: C[M,N] = A[M,K] * B[N,K]^T + bias[N] ---------
__global__ __launch_bounds__(256)
void gemm_nt_f32(const float* __restrict__ A, const float* __restrict__ Bm,
                 const float* __restrict__ bias, float* __restrict__ C,
                 int M, int N, int K)
{
    __shared__ float As[16][132];
    __shared__ float Bs[16][132];
    const int tid = threadIdx.x;
    const int tx = tid & 15, ty = tid >> 4;
    const int m0 = blockIdx.x * 128, n0 = blockIdx.y * 128;

    float acc[8][8];
    #pragma unroll
    for (int i = 0; i < 8; ++i)
        #pragma unroll
        for (int j = 0; j < 8; ++j) acc[i][j] = 0.f;

    const int lrow0 = tid >> 2;
    const int lk    = (tid & 3) * 4;

    for (int kc = 0; kc < K; kc += 16) {
        #pragma unroll
        for (int l = 0; l < 2; ++l) {
            int row = lrow0 + l * 64;
            float4 av = *(const float4*)&A[(size_t)(m0 + row) * K + kc + lk];
            float4 bv = *(const float4*)&Bm[(size_t)(n0 + row) * K + kc + lk];
            As[lk+0][row] = av.x; As[lk+1][row] = av.y;
            As[lk+2][row] = av.z; As[lk+3][row] = av.w;
            Bs[lk+0][row] = bv.x; Bs[lk+1][row] = bv.y;
            Bs[lk+2][row] = bv.z; Bs[lk+3][row] = bv.w;
        }
        __syncthreads();
        #pragma unroll
        for (int k = 0; k < 16; ++k) {
            float4 a0 = *(const float4*)&As[k][ty*8];
            float4 a1 = *(const float4*)&As[k][ty*8+4];
            float4 b0 = *(const float4*)&Bs[k][tx*8];
            float4 b1 = *(const float4*)&Bs[k][tx*8+4];
            float a[8] = {a0.x,a0.y,a0.z,a0.w,a1.x,a1.y,a1.z,a1.w};
            float b[8] = {b0.x,b0.y,b0.z,b0.w,b1.x,b1.y,b1.z,b1.w};
            #pragma unroll
            for (int i = 0; i < 8; ++i)
                #pragma unroll
                for (int j = 0; j < 8; ++j)
                    acc[i][j] = fmaf(a[i], b[j], acc[i][j]);
        }
        __syncthreads();
    }

    float bsr[8];
    #pragma unroll
    for (int j = 0; j < 8; ++j) bsr[j] = bias[n0 + tx*8 + j];
    #pragma unroll
    for (int i = 0; i < 8; ++i) {
        size_t r = (size_t)(m0 + ty*8 + i) * N + n0 + tx*8;
        float4 o0 = make_float4(acc[i][0]+bsr[0], acc[i][1]+bsr[1],
                                acc[i][2]+bsr[2], acc[i][3]+bsr[3]);
        float4 o1 = make_float4(acc[i][4]+bsr[4], acc[i][5]+bsr[5],
                                acc[i][6]+bsr[6], acc[i][7]+bsr[7]);
        *(float4*)&C[r]     = o0;
        *(float4*)&C[r + 4] = o1;
    }
}

// ------- normalize q,k; split to bf16 hi/lo; layout [BH][S][D] --------------
__global__ __launch_bounds__(256)
void normalize_split_qk(const float* __restrict__ qkv,
                        unsigned short* __restrict__ qh, unsigned short* __restrict__ ql,
                        unsigned short* __restrict__ kh, unsigned short* __restrict__ kl)
{
    int w    = blockIdx.x * 4 + (threadIdx.x >> 6);
    int lane = threadIdx.x & 63;
    int n = w >> 4, h = w & 15;
    int b = n >> 11, s = n & 2047;
    const float* base = qkv + (size_t)n * 3 * HIDN + h * HD;
    float q = base[lane], k = base[HIDN + lane];
    float qs = q * q, ks = k * k;
    #pragma unroll
    for (int o = 32; o; o >>= 1) { qs += __shfl_xor(qs, o); ks += __shfl_xor(ks, o); }
    q *= 1.0f / fmaxf(sqrtf(qs), 1e-12f);
    k *= 1.0f / fmaxf(sqrtf(ks), 1e-12f);
    size_t idx = ((size_t)((b * NH + h) * SEQ + s)) * HD + lane;
    unsigned short qhb = f2bf(q); qh[idx] = qhb; ql[idx] = f2bf(q - bf2f(qhb));
    unsigned short khb = f2bf(k); kh[idx] = khb; kl[idx] = f2bf(k - bf2f(khb));
}

// ------- V: split hi/lo and transpose to [BH][D][S] -------------------------
__global__ __launch_bounds__(256)
void v_transpose_split(const float* __restrict__ qkv,
                       unsigned short* __restrict__ vth, unsigned short* __restrict__ vtl)
{
    __shared__ float Ls[64][65];
    int bh = blockIdx.y, s0 = blockIdx.x * 64;
    int b = bh >> 4, h = bh & 15;
    int tid = threadIdx.x;
    #pragma unroll
    for (int i = 0; i < 4; ++i) {
        int idx = tid + i * 256;
        int row = idx >> 4, c4 = (idx & 15) * 4;
        float4 v = *(const float4*)&qkv[((size_t)(b * SEQ + s0 + row)) * 3 * HIDN
                                        + 2 * HIDN + h * HD + c4];
        Ls[row][c4+0] = v.x; Ls[row][c4+1] = v.y; Ls[row][c4+2] = v.z; Ls[row][c4+3] = v.w;
    }
    __syncthreads();
    int d = tid >> 2, sb = (tid & 3) * 16;
    unsigned short hi[16], lo[16];
    #pragma unroll
    for (int j = 0; j < 16; ++j) {
        float f = Ls[sb + j][d];
        unsigned short hb = f2bf(f);
        hi[j] = hb; lo[j] = f2bf(f - bf2f(hb));
    }
    size_t o = ((size_t)bh * HD + d) * SEQ + s0 + sb;
    *(uint4*)&vth[o]     = *(uint4*)&hi[0];
    *(uint4*)&vth[o + 8] = *(uint4*)&hi[8];
    *(uint4*)&vtl[o]     = *(uint4*)&lo[0];
    *(uint4*)&vtl[o + 8] = *(uint4*)&lo[8];
}

// ------- col[bh,t] = (sum_s score(q_s . k_t))^-0.5 via MFMA -----------------
// wave computes 16 t-rows (A = K), loops s-tiles of 64 (B = Q^T)
__global__ __launch_bounds__(256)
void col_sum_mfma(const unsigned short* __restrict__ qh, const unsigned short* __restrict__ ql,
                  const unsigned short* __restrict__ kh, const unsigned short* __restrict__ kl,
                  float* __restrict__ col)
{
    int bh = blockIdx.y, t0 = blockIdx.x * 64;
    int tid = threadIdx.x, w = tid >> 6, lane = tid & 63, ln = lane & 15, lq = lane >> 4;
    int m0 = t0 + w * 16;
    size_t rowK = ((size_t)bh * SEQ + m0 + ln) * HD;
    bf16x8 kfh0 = ldfrag(kh + rowK + lq*8), kfh1 = ldfrag(kh + rowK + 32 + lq*8);
    bf16x8 kfl0 = ldfrag(kl + rowK + lq*8), kfl1 = ldfrag(kl + rowK + 32 + lq*8);

    float cacc[4] = {0.f, 0.f, 0.f, 0.f};
    for (int s0 = 0; s0 < SEQ; s0 += 64) {
        __syncthreads();   // keep waves aligned for L1 reuse of Q frags
        #pragma unroll
        for (int nt = 0; nt < 4; ++nt) {
            size_t rowQ = ((size_t)bh * SEQ + s0 + nt * 16 + ln) * HD;
            bf16x8 qfh0 = ldfrag(qh + rowQ + lq*8), qfh1 = ldfrag(qh + rowQ + 32 + lq*8);
            bf16x8 qfl0 = ldfrag(ql + rowQ + lq*8), qfl1 = ldfrag(ql + rowQ + 32 + lq*8);
            f32x4 acc = {0.f, 0.f, 0.f, 0.f};
            acc = mfma16(kfh0, qfh0, acc); acc = mfma16(kfh1, qfh1, acc);
            acc = mfma16(kfh0, qfl0, acc); acc = mfma16(kfh1, qfl1, acc);
            acc = mfma16(kfl0, qfh0, acc); acc = mfma16(kfl1, qfh1, acc);
            #pragma unroll
            for (int r = 0; r < 4; ++r) cacc[r] += score_fn(acc[r]);
        }
    }
    #pragma unroll
    for (int r = 0; r < 4; ++r) {
        float v = cacc[r];
        v += __shfl_xor(v, 1); v += __shfl_xor(v, 2);
        v += __shfl_xor(v, 4); v += __shfl_xor(v, 8);
        if (ln == 0) col[(size_t)bh * SEQ + m0 + lq * 4 + r] = 1.0f / sqrtf(v);
    }
}

// ------- fused scores -> W -> W@V via MFMA ----------------------------------
// wave: 16 s-rows; per t-tile(64): QK (3-pass split), score, per-wave LDS
// transpose to A-layout, PV (V hi/lo split). No block barrier dependencies.
#define WSTR 72
__global__ __launch_bounds__(256)
void attn_mfma(const unsigned short* __restrict__ qh, const unsigned short* __restrict__ ql,
               const unsigned short* __restrict__ kh, const unsigned short* __restrict__ kl,
               const unsigned short* __restrict__ vth, const unsigned short* __restrict__ vtl,
               const float* __restrict__ col, float* __restrict__ ctx)
{
    __shared__ __align__(16) unsigned short Ws[4][16 * WSTR];
    int bh = blockIdx.y;
    int b = bh >> 4, h = bh & 15;
    int tid = threadIdx.x, w = tid >> 6, lane = tid & 63, ln = lane & 15, lq = lane >> 4;
    int m0 = blockIdx.x * 64 + w * 16;
    unsigned short* ws = Ws[w];

    size_t rowQ = ((size_t)bh * SEQ + m0 + ln) * HD;
    bf16x8 qfh0 = ldfrag(qh + rowQ + lq*8), qfh1 = ldfrag(qh + rowQ + 32 + lq*8);
    bf16x8 qfl0 = ldfrag(ql + rowQ + lq*8), qfl1 = ldfrag(ql + rowQ + 32 + lq*8);

    f32x4 num[4];
    #pragma unroll
    for (int nt = 0; nt < 4; ++nt) num[nt] = (f32x4){0.f, 0.f, 0.f, 0.f};
    float dpart[4] = {0.f, 0.f, 0.f, 0.f};

    for (int t0 = 0; t0 < SEQ; t0 += 64) {
        __syncthreads();   // wave alignment only (L1 reuse); no data dependence
        // ---- QK^T + score + col-scale -> Ws (per-wave) ----
        #pragma unroll
        for (int nt = 0; nt < 4; ++nt) {
            size_t rowK = ((size_t)bh * SEQ + t0 + nt * 16 + ln) * HD;
            bf16x8 kfh0 = ldfrag(kh + rowK + lq*8), kfh1 = ldfrag(kh + rowK + 32 + lq*8);
            bf16x8 kfl0 = ldfrag(kl + rowK + lq*8), kfl1 = ldfrag(kl + rowK + 32 + lq*8);
            f32x4 acc = {0.f, 0.f, 0.f, 0.f};
            acc = mfma16(qfh0, kfh0, acc); acc = mfma16(qfh1, kfh1, acc);
            acc = mfma16(qfh0, kfl0, acc); acc = mfma16(qfh1, kfl1, acc);
            acc = mfma16(qfl0, kfh0, acc); acc = mfma16(qfl1, kfh1, acc);
            float cl = col[(size_t)bh * SEQ + t0 + nt * 16 + ln];
            #pragma unroll
            for (int r = 0; r < 4; ++r) {
                float wv = score_fn(acc[r]) * cl;
                unsigned short wb = f2bf(wv);
                dpart[r] += bf2f(wb);       // denom consistent with bf16 numerator
                ws[(lq * 4 + r) * WSTR + nt * 16 + ln] = wb;
            }
        }
        // ---- read W in A-layout, PV with V hi/lo ----
        bf16x8 wa0 = ldfrag(ws + ln * WSTR + lq*8);
        bf16x8 wa1 = ldfrag(ws + ln * WSTR + 32 + lq*8);
        #pragma unroll
        for (int nt = 0; nt < 4; ++nt) {
            size_t rowV = ((size_t)bh * HD + nt * 16 + ln) * SEQ + t0;
            bf16x8 vh0 = ldfrag(vth + rowV + lq*8), vh1 = ldfrag(vth + rowV + 32 + lq*8);
            bf16x8 vl0 = ldfrag(vtl + rowV + lq*8), vl1 = ldfrag(vtl + rowV + 32 + lq*8);
            num[nt] = mfma16(wa0, vh0, num[nt]); num[nt] = mfma16(wa1, vh1, num[nt]);
            num[nt] = mfma16(wa0, vl0, num[nt]); num[nt] = mfma16(wa1, vl1, num[nt]);
        }
    }

    #pragma unroll
    for (int r = 0; r < 4; ++r) {
        float v = dpart[r];
        v += __shfl_xor(v, 1); v += __shfl_xor(v, 2);
        v += __shfl_xor(v, 4); v += __shfl_xor(v, 8);
        dpart[r] = v;
    }
    #pragma unroll
    for (int r = 0; r < 4; ++r) {
        float inv = 1.0f / fmaxf(dpart[r], 1e-12f);
        int s = m0 + lq * 4 + r;
        #pragma unroll
        for (int nt = 0; nt < 4; ++nt)
            ctx[((size_t)(b * SEQ + s)) * HIDN + h * HD + nt * 16 + ln] = num[nt][r] * inv;
    }
}

extern "C" void kernel_launch(void* const* d_in, const int* in_sizes, int n_in,
                              void* d_out, int out_size, void* d_ws, size_t ws_size,
                              hipStream_t stream) {
    const float* x      = (const float*)d_in[0];
    const float* qkv_w  = (const float*)d_in[1];
    const float* qkv_b  = (const float*)d_in[2];
    const float* out_w  = (const float*)d_in[3];
    const float* out_b  = (const float*)d_in[4];
    float* out = (float*)d_out;

    float* qkv = (float*)d_ws;                            // 50.3 MB
    float* ctx = qkv + (size_t)ROWS * 3 * HIDN;           // 16.8 MB
    float* col = ctx + (size_t)ROWS * HIDN;               // 0.26 MB
    size_t NT = (size_t)BH * SEQ * HD;                    // 4.19M elems
    unsigned short* qhp = (unsigned short*)(col + (size_t)BH * SEQ);
    unsigned short* qlp = qhp + NT;
    unsigned short* khp = qlp + NT;
    unsigned short* klp = khp + NT;
    unsigned short* vth = klp + NT;
    unsigned short* vtl = vth + NT;                       // 6 x 8.4 MB

    gemm_nt_f32<<<dim3(ROWS/128, 3*HIDN/128), 256, 0, stream>>>(
        x, qkv_w, qkv_b, qkv, ROWS, 3*HIDN, HIDN);
    normalize_split_qk<<<ROWS*NH/4, 256, 0, stream>>>(qkv, qhp, qlp, khp, klp);
    v_transpose_split<<<dim3(SEQ/64, BH), 256, 0, stream>>>(qkv, vth, vtl);
    col_sum_mfma<<<dim3(SEQ/64, BH), 256, 0, stream>>>(qhp, qlp, khp, klp, col);
    attn_mfma<<<dim3(SEQ/64, BH), 256, 0, stream>>>(qhp, qlp, khp, klp, vth, vtl, col, ctx);
    gemm_nt_f32<<<dim3(ROWS/128, HIDN/128), 256, 0, stream>>>(
        ctx, out_w, out_b, out, ROWS, HIDN, HIDN);
}

// Round 4
// 638.649 us; speedup vs baseline: 2.3112x; 1.8917x over previous
//
#include <hip/hip_runtime.h>
#include <math.h>

#define NH   16
#define HD   64
#define HIDN 1024
#define NB   2
#define SEQ  2048
#define ROWS (NB*SEQ)   // 4096
#define BH   (NB*NH)    // 32

typedef __attribute__((ext_vector_type(8))) short bf16x8;
typedef __attribute__((ext_vector_type(8))) _Float16 f16x8;
typedef __attribute__((ext_vector_type(4))) float f32x4;
typedef _Float16 f16;

__device__ __forceinline__ unsigned short f2bf(float f) {
    unsigned u = __float_as_uint(f);
    u += 0x7FFF + ((u >> 16) & 1);          // RNE
    return (unsigned short)(u >> 16);
}
__device__ __forceinline__ float bf2f(unsigned short h) {
    return __uint_as_float(((unsigned)h) << 16);
}
__device__ __forceinline__ bf16x8 ldfrag(const unsigned short* p) {
    return *(const bf16x8*)p;
}
__device__ __forceinline__ f16x8 ldfragh(const f16* p) {
    return *(const f16x8*)p;
}
__device__ __forceinline__ f32x4 mfma16(bf16x8 a, bf16x8 b, f32x4 c) {
    return __builtin_amdgcn_mfma_f32_16x16x32_bf16(a, b, c, 0, 0, 0);
}
__device__ __forceinline__ f32x4 mfma16h(f16x8 a, f16x8 b, f32x4 c) {
    return __builtin_amdgcn_mfma_f32_16x16x32_f16(a, b, c, 0, 0, 0);
}

// score = (1 + acos(clip(c)))^-65, fast path:
// acos(1-u) = sqrt(2u) * (1 + u/12 + 3u^2/160 + 5u^3/896 + 35u^4/18432 + 63u^5/90112)
// rel err < 2e-5 for u <= 0.8 (the only region where scores matter relatively)
__device__ __forceinline__ float score_fast(float c) {
    float u = 1.0f - c;
    u = fminf(fmaxf(u, 1e-7f), 2.0f - 1e-7f);
    float s = __builtin_amdgcn_sqrtf(2.0f * u);
    float p = fmaf(u, 6.9907e-4f, 1.8988e-3f);
    p = fmaf(u, p, 5.5804e-3f);
    p = fmaf(u, p, 1.8750e-2f);
    p = fmaf(u, p, 8.3333336e-2f);
    p = fmaf(u, p, 1.0f);
    float g = s * p;
    float l = __builtin_amdgcn_logf(1.0f + g);      // log2(1+g)
    return __builtin_amdgcn_exp2f(-65.0f * l);
}

// ---------------- f32 -> f16 convert (n % 8 == 0) ---------------------------
__global__ __launch_bounds__(256)
void conv_f16(const float* __restrict__ src, f16* __restrict__ dst) {
    int i = (blockIdx.x * 256 + threadIdx.x) * 8;
    float4 a = *(const float4*)(src + i);
    float4 b = *(const float4*)(src + i + 4);
    f16x8 o = { (f16)a.x, (f16)a.y, (f16)a.z, (f16)a.w,
                (f16)b.x, (f16)b.y, (f16)b.z, (f16)b.w };
    *(f16x8*)(dst + i) = o;
}

// -------- fp16 MFMA NT GEMM: C[M,N] = A[M,K]*B[N,K]^T + bias[N], C f32 ------
// 128x128 tile, BK=32, 256 thr / 4 waves (64x64 quadrants), m93-style staging
__global__ __launch_bounds__(256)
void gemm_nt_f16(const f16* __restrict__ A, const f16* __restrict__ B,
                 const float* __restrict__ bias, float* __restrict__ C,
                 int M, int N, int K)
{
    __shared__ f16 As[128 * 32];
    __shared__ f16 Bs[128 * 32];
    const int tid = threadIdx.x;
    const int lane = tid & 63, w = tid >> 6;
    const int ln = lane & 15, lq = lane >> 4;
    const int wm = (w >> 1) * 64, wn = (w & 1) * 64;
    const int m0 = blockIdx.x * 128, n0 = blockIdx.y * 128;

    const int srow = tid >> 1;            // 0..127
    const int scol = (tid & 1) * 16;      // 0 / 16
    const f16* Ag = A + (size_t)(m0 + srow) * K + scol;
    const f16* Bg = B + (size_t)(n0 + srow) * K + scol;
    f16* Asw = As + srow * 32 + scol;
    f16* Bsw = Bs + srow * 32 + scol;

    f32x4 acc[4][4];
    #pragma unroll
    for (int i = 0; i < 4; ++i)
        #pragma unroll
        for (int j = 0; j < 4; ++j) acc[i][j] = (f32x4){0.f, 0.f, 0.f, 0.f};

    for (int kc = 0; kc < K; kc += 32) {
        uint4 a0 = *(const uint4*)(Ag + kc);
        uint4 a1 = *(const uint4*)(Ag + kc + 8);
        uint4 b0 = *(const uint4*)(Bg + kc);
        uint4 b1 = *(const uint4*)(Bg + kc + 8);
        __syncthreads();
        *(uint4*)Asw = a0; *(uint4*)(Asw + 8) = a1;
        *(uint4*)Bsw = b0; *(uint4*)(Bsw + 8) = b1;
        __syncthreads();
        f16x8 af[4], bf[4];
        #pragma unroll
        for (int i = 0; i < 4; ++i)
            af[i] = *(const f16x8*)&As[(wm + i * 16 + ln) * 32 + lq * 8];
        #pragma unroll
        for (int j = 0; j < 4; ++j)
            bf[j] = *(const f16x8*)&Bs[(wn + j * 16 + ln) * 32 + lq * 8];
        #pragma unroll
        for (int i = 0; i < 4; ++i)
            #pragma unroll
            for (int j = 0; j < 4; ++j)
                acc[i][j] = mfma16h(af[i], bf[j], acc[i][j]);
    }

    #pragma unroll
    for (int i = 0; i < 4; ++i) {
        #pragma unroll
        for (int j = 0; j < 4; ++j) {
            int colIdx = n0 + wn + j * 16 + ln;
            float bs = bias[colIdx];
            #pragma unroll
            for (int r = 0; r < 4; ++r) {
                int row = m0 + wm + i * 16 + lq * 4 + r;
                C[(size_t)row * N + colIdx] = acc[i][j][r] + bs;
            }
        }
    }
}

// ------- normalize q,k -> f16; layout [BH][S][D] ----------------------------
__global__ __launch_bounds__(256)
void normalize_qk_f16(const float* __restrict__ qkv,
                      f16* __restrict__ qf, f16* __restrict__ kf)
{
    int w    = blockIdx.x * 4 + (threadIdx.x >> 6);
    int lane = threadIdx.x & 63;
    int n = w >> 4, h = w & 15;
    int b = n >> 11, s = n & 2047;
    const float* base = qkv + (size_t)n * 3 * HIDN + h * HD;
    float q = base[lane], k = base[HIDN + lane];
    float qs = q * q, ks = k * k;
    #pragma unroll
    for (int o = 32; o; o >>= 1) { qs += __shfl_xor(qs, o); ks += __shfl_xor(ks, o); }
    q *= 1.0f / fmaxf(sqrtf(qs), 1e-12f);
    k *= 1.0f / fmaxf(sqrtf(ks), 1e-12f);
    size_t idx = ((size_t)((b * NH + h) * SEQ + s)) * HD + lane;
    qf[idx] = (f16)q;
    kf[idx] = (f16)k;
}

// ------- V: split bf16 hi/lo, transpose to [BH][D][S] -----------------------
__global__ __launch_bounds__(256)
void v_transpose_split(const float* __restrict__ qkv,
                       unsigned short* __restrict__ vth, unsigned short* __restrict__ vtl)
{
    __shared__ float Ls[64][65];
    int bh = blockIdx.y, s0 = blockIdx.x * 64;
    int b = bh >> 4, h = bh & 15;
    int tid = threadIdx.x;
    #pragma unroll
    for (int i = 0; i < 4; ++i) {
        int idx = tid + i * 256;
        int row = idx >> 4, c4 = (idx & 15) * 4;
        float4 v = *(const float4*)&qkv[((size_t)(b * SEQ + s0 + row)) * 3 * HIDN
                                        + 2 * HIDN + h * HD + c4];
        Ls[row][c4+0] = v.x; Ls[row][c4+1] = v.y; Ls[row][c4+2] = v.z; Ls[row][c4+3] = v.w;
    }
    __syncthreads();
    int d = tid >> 2, sb = (tid & 3) * 16;
    unsigned short hi[16], lo[16];
    #pragma unroll
    for (int j = 0; j < 16; ++j) {
        float f = Ls[sb + j][d];
        unsigned short hb = f2bf(f);
        hi[j] = hb; lo[j] = f2bf(f - bf2f(hb));
    }
    size_t o = ((size_t)bh * HD + d) * SEQ + s0 + sb;
    *(uint4*)&vth[o]     = *(uint4*)&hi[0];
    *(uint4*)&vth[o + 8] = *(uint4*)&hi[8];
    *(uint4*)&vtl[o]     = *(uint4*)&lo[0];
    *(uint4*)&vtl[o + 8] = *(uint4*)&lo[8];
}

// ------- col[bh,t] = (sum_s score(q_s . k_t))^-0.5, fp16 QK MFMA ------------
__global__ __launch_bounds__(256)
void col_sum_f16(const f16* __restrict__ qf, const f16* __restrict__ kf,
                 float* __restrict__ col)
{
    int bh = blockIdx.y, t0 = blockIdx.x * 64;
    int tid = threadIdx.x, w = tid >> 6, lane = tid & 63, ln = lane & 15, lq = lane >> 4;
    int m0 = t0 + w * 16;
    size_t rowK = ((size_t)bh * SEQ + m0 + ln) * HD;
    f16x8 kf0 = ldfragh(kf + rowK + lq * 8), kf1 = ldfragh(kf + rowK + 32 + lq * 8);

    float cacc[4] = {0.f, 0.f, 0.f, 0.f};
    for (int s0 = 0; s0 < SEQ; s0 += 64) {
        __syncthreads();   // wave alignment for L1 reuse
        f16x8 qfr[4][2];
        #pragma unroll
        for (int nt = 0; nt < 4; ++nt) {
            size_t rowQ = ((size_t)bh * SEQ + s0 + nt * 16 + ln) * HD;
            qfr[nt][0] = ldfragh(qf + rowQ + lq * 8);
            qfr[nt][1] = ldfragh(qf + rowQ + 32 + lq * 8);
        }
        f32x4 sacc[4];
        #pragma unroll
        for (int nt = 0; nt < 4; ++nt) {
            sacc[nt] = (f32x4){0.f, 0.f, 0.f, 0.f};
            sacc[nt] = mfma16h(kf0, qfr[nt][0], sacc[nt]);
            sacc[nt] = mfma16h(kf1, qfr[nt][1], sacc[nt]);
        }
        #pragma unroll
        for (int nt = 0; nt < 4; ++nt)
            #pragma unroll
            for (int r = 0; r < 4; ++r) cacc[r] += score_fast(sacc[nt][r]);
    }
    #pragma unroll
    for (int r = 0; r < 4; ++r) {
        float v = cacc[r];
        v += __shfl_xor(v, 1); v += __shfl_xor(v, 2);
        v += __shfl_xor(v, 4); v += __shfl_xor(v, 8);
        if (ln == 0) col[(size_t)bh * SEQ + m0 + lq * 4 + r] = 1.0f / sqrtf(v);
    }
}

// ------- fused scores -> W(bf16) -> W@V, fp16 QK + bf16 hi/lo PV ------------
#define WSTR 72
__global__ __launch_bounds__(256)
void attn_f16(const f16* __restrict__ qf, const f16* __restrict__ kf,
              const unsigned short* __restrict__ vth, const unsigned short* __restrict__ vtl,
              const float* __restrict__ col, f16* __restrict__ ctx)
{
    __shared__ __align__(16) unsigned short Ws[4][16 * WSTR];
    int bh = blockIdx.y;
    int b = bh >> 4, h = bh & 15;
    int tid = threadIdx.x, w = tid >> 6, lane = tid & 63, ln = lane & 15, lq = lane >> 4;
    int m0 = blockIdx.x * 64 + w * 16;
    unsigned short* ws = Ws[w];

    size_t rowQ = ((size_t)bh * SEQ + m0 + ln) * HD;
    f16x8 qf0 = ldfragh(qf + rowQ + lq * 8), qf1 = ldfragh(qf + rowQ + 32 + lq * 8);

    f32x4 num[4];
    #pragma unroll
    for (int nt = 0; nt < 4; ++nt) num[nt] = (f32x4){0.f, 0.f, 0.f, 0.f};
    float dpart[4] = {0.f, 0.f, 0.f, 0.f};

    for (int t0 = 0; t0 < SEQ; t0 += 64) {
        __syncthreads();   // wave alignment only; Ws is per-wave
        // hoisted K-frag + col loads
        f16x8 kfr[4][2]; float cl[4];
        #pragma unroll
        for (int nt = 0; nt < 4; ++nt) {
            size_t rowK = ((size_t)bh * SEQ + t0 + nt * 16 + ln) * HD;
            kfr[nt][0] = ldfragh(kf + rowK + lq * 8);
            kfr[nt][1] = ldfragh(kf + rowK + 32 + lq * 8);
            cl[nt] = col[(size_t)bh * SEQ + t0 + nt * 16 + ln];
        }
        // QK^T (single fp16 pass)
        f32x4 sacc[4];
        #pragma unroll
        for (int nt = 0; nt < 4; ++nt) {
            sacc[nt] = (f32x4){0.f, 0.f, 0.f, 0.f};
            sacc[nt] = mfma16h(qf0, kfr[nt][0], sacc[nt]);
            sacc[nt] = mfma16h(qf1, kfr[nt][1], sacc[nt]);
        }
        // score + col-scale -> Ws (bf16; values ~1e-11, below fp16 range!)
        #pragma unroll
        for (int nt = 0; nt < 4; ++nt) {
            #pragma unroll
            for (int r = 0; r < 4; ++r) {
                float wv = score_fast(sacc[nt][r]) * cl[nt];
                unsigned short wb = f2bf(wv);
                dpart[r] += bf2f(wb);
                ws[(lq * 4 + r) * WSTR + nt * 16 + ln] = wb;
            }
        }
        // W in A-layout, PV with V hi/lo bf16
        bf16x8 wa0 = ldfrag(ws + ln * WSTR + lq * 8);
        bf16x8 wa1 = ldfrag(ws + ln * WSTR + 32 + lq * 8);
        #pragma unroll
        for (int nt = 0; nt < 4; ++nt) {
            size_t rowV = ((size_t)bh * HD + nt * 16 + ln) * SEQ + t0;
            bf16x8 vh0 = ldfrag(vth + rowV + lq * 8), vh1 = ldfrag(vth + rowV + 32 + lq * 8);
            bf16x8 vl0 = ldfrag(vtl + rowV + lq * 8), vl1 = ldfrag(vtl + rowV + 32 + lq * 8);
            num[nt] = mfma16(wa0, vh0, num[nt]); num[nt] = mfma16(wa1, vh1, num[nt]);
            num[nt] = mfma16(wa0, vl0, num[nt]); num[nt] = mfma16(wa1, vl1, num[nt]);
        }
    }

    #pragma unroll
    for (int r = 0; r < 4; ++r) {
        float v = dpart[r];
        v += __shfl_xor(v, 1); v += __shfl_xor(v, 2);
        v += __shfl_xor(v, 4); v += __shfl_xor(v, 8);
        dpart[r] = v;
    }
    #pragma unroll
    for (int r = 0; r < 4; ++r) {
        float inv = 1.0f / fmaxf(dpart[r], 1e-12f);
        int s = m0 + lq * 4 + r;
        #pragma unroll
        for (int nt = 0; nt < 4; ++nt)
            ctx[((size_t)(b * SEQ + s)) * HIDN + h * HD + nt * 16 + ln] =
                (f16)(num[nt][r] * inv);
    }
}

extern "C" void kernel_launch(void* const* d_in, const int* in_sizes, int n_in,
                              void* d_out, int out_size, void* d_ws, size_t ws_size,
                              hipStream_t stream) {
    const float* x      = (const float*)d_in[0];
    const float* qkv_w  = (const float*)d_in[1];
    const float* qkv_b  = (const float*)d_in[2];
    const float* out_w  = (const float*)d_in[3];
    const float* out_b  = (const float*)d_in[4];
    float* out = (float*)d_out;

    const size_t NTT = (size_t)BH * SEQ * HD;             // 4.19M
    float* qkv = (float*)d_ws;                            // 12.58M f32
    float* col = qkv + (size_t)ROWS * 3 * HIDN;           // 65536 f32
    f16* xh    = (f16*)(col + (size_t)BH * SEQ);
    f16* wqh   = xh + (size_t)ROWS * HIDN;
    f16* woh   = wqh + (size_t)3 * HIDN * HIDN;
    f16* ctxh  = woh + (size_t)HIDN * HIDN;
    f16* qfp   = ctxh + (size_t)ROWS * HIDN;
    f16* kfp   = qfp + NTT;
    unsigned short* vth = (unsigned short*)(kfp + NTT);
    unsigned short* vtl = vth + NTT;

    conv_f16<<<ROWS*HIDN/2048, 256, 0, stream>>>(x, xh);
    conv_f16<<<3*HIDN*HIDN/2048, 256, 0, stream>>>(qkv_w, wqh);
    conv_f16<<<HIDN*HIDN/2048, 256, 0, stream>>>(out_w, woh);

    gemm_nt_f16<<<dim3(ROWS/128, 3*HIDN/128), 256, 0, stream>>>(
        xh, wqh, qkv_b, qkv, ROWS, 3*HIDN, HIDN);
    normalize_qk_f16<<<ROWS*NH/4, 256, 0, stream>>>(qkv, qfp, kfp);
    v_transpose_split<<<dim3(SEQ/64, BH), 256, 0, stream>>>(qkv, vth, vtl);
    col_sum_f16<<<dim3(SEQ/64, BH), 256, 0, stream>>>(qfp, kfp, col);
    attn_f16<<<dim3(SEQ/64, BH), 256, 0, stream>>>(qfp, kfp, vth, vtl, col, ctxh);
    gemm_nt_f16<<<dim3(ROWS/128, HIDN/128), 256, 0, stream>>>(
        ctxh, woh, out_b, out, ROWS, HIDN, HIDN);
}

// Round 5
// 521.772 us; speedup vs baseline: 2.8289x; 1.2240x over previous
//
#include <hip/hip_runtime.h>
#include <math.h>

#define NH   16
#define HD   64
#define HIDN 1024
#define NB   2
#define SEQ  2048
#define ROWS (NB*SEQ)   // 4096
#define BH   (NB*NH)    // 32

typedef __attribute__((ext_vector_type(8))) short bf16x8;
typedef __attribute__((ext_vector_type(8))) _Float16 f16x8;
typedef __attribute__((ext_vector_type(4))) float f32x4;
typedef _Float16 f16;

__device__ __forceinline__ unsigned short f2bf(float f) {
    unsigned u = __float_as_uint(f);
    u += 0x7FFF + ((u >> 16) & 1);          // RNE
    return (unsigned short)(u >> 16);
}
__device__ __forceinline__ float bf2f(unsigned short h) {
    return __uint_as_float(((unsigned)h) << 16);
}
__device__ __forceinline__ bf16x8 ldfrag(const unsigned short* p) {
    return *(const bf16x8*)p;
}
__device__ __forceinline__ f16x8 ldfragh(const f16* p) {
    return *(const f16x8*)p;
}
__device__ __forceinline__ f32x4 mfma16(bf16x8 a, bf16x8 b, f32x4 c) {
    return __builtin_amdgcn_mfma_f32_16x16x32_bf16(a, b, c, 0, 0, 0);
}
__device__ __forceinline__ f32x4 mfma16h(f16x8 a, f16x8 b, f32x4 c) {
    return __builtin_amdgcn_mfma_f32_16x16x32_f16(a, b, c, 0, 0, 0);
}

// score = (1 + acos(clip(c)))^-65, fast path:
// acos(1-u) = sqrt(2u) * (1 + u/12 + 3u^2/160 + 5u^3/896 + ...)
__device__ __forceinline__ float score_fast(float c) {
    float u = 1.0f - c;
    u = fminf(fmaxf(u, 1e-7f), 2.0f - 1e-7f);
    float s = __builtin_amdgcn_sqrtf(2.0f * u);
    float p = fmaf(u, 6.9907e-4f, 1.8988e-3f);
    p = fmaf(u, p, 5.5804e-3f);
    p = fmaf(u, p, 1.8750e-2f);
    p = fmaf(u, p, 8.3333336e-2f);
    p = fmaf(u, p, 1.0f);
    float g = s * p;
    float l = __builtin_amdgcn_logf(1.0f + g);      // log2(1+g)
    return __builtin_amdgcn_exp2f(-65.0f * l);
}

// ---------------- f32 -> f16 convert (n % 8 == 0) ---------------------------
__global__ __launch_bounds__(256)
void conv_f16(const float* __restrict__ src, f16* __restrict__ dst) {
    int i = (blockIdx.x * 256 + threadIdx.x) * 8;
    float4 a = *(const float4*)(src + i);
    float4 b = *(const float4*)(src + i + 4);
    f16x8 o = { (f16)a.x, (f16)a.y, (f16)a.z, (f16)a.w,
                (f16)b.x, (f16)b.y, (f16)b.z, (f16)b.w };
    *(f16x8*)(dst + i) = o;
}

// -------- fp16 MFMA NT GEMM: C[M,N] = A[M,K]*B[N,K]^T + bias[N], C f32 ------
__global__ __launch_bounds__(256)
void gemm_nt_f16(const f16* __restrict__ A, const f16* __restrict__ B,
                 const float* __restrict__ bias, float* __restrict__ C,
                 int M, int N, int K)
{
    __shared__ f16 As[128 * 32];
    __shared__ f16 Bs[128 * 32];
    const int tid = threadIdx.x;
    const int lane = tid & 63, w = tid >> 6;
    const int ln = lane & 15, lq = lane >> 4;
    const int wm = (w >> 1) * 64, wn = (w & 1) * 64;
    const int m0 = blockIdx.x * 128, n0 = blockIdx.y * 128;

    const int srow = tid >> 1;
    const int scol = (tid & 1) * 16;
    const f16* Ag = A + (size_t)(m0 + srow) * K + scol;
    const f16* Bg = B + (size_t)(n0 + srow) * K + scol;
    f16* Asw = As + srow * 32 + scol;
    f16* Bsw = Bs + srow * 32 + scol;

    f32x4 acc[4][4];
    #pragma unroll
    for (int i = 0; i < 4; ++i)
        #pragma unroll
        for (int j = 0; j < 4; ++j) acc[i][j] = (f32x4){0.f, 0.f, 0.f, 0.f};

    for (int kc = 0; kc < K; kc += 32) {
        uint4 a0 = *(const uint4*)(Ag + kc);
        uint4 a1 = *(const uint4*)(Ag + kc + 8);
        uint4 b0 = *(const uint4*)(Bg + kc);
        uint4 b1 = *(const uint4*)(Bg + kc + 8);
        __syncthreads();
        *(uint4*)Asw = a0; *(uint4*)(Asw + 8) = a1;
        *(uint4*)Bsw = b0; *(uint4*)(Bsw + 8) = b1;
        __syncthreads();
        f16x8 af[4], bf[4];
        #pragma unroll
        for (int i = 0; i < 4; ++i)
            af[i] = *(const f16x8*)&As[(wm + i * 16 + ln) * 32 + lq * 8];
        #pragma unroll
        for (int j = 0; j < 4; ++j)
            bf[j] = *(const f16x8*)&Bs[(wn + j * 16 + ln) * 32 + lq * 8];
        #pragma unroll
        for (int i = 0; i < 4; ++i)
            #pragma unroll
            for (int j = 0; j < 4; ++j)
                acc[i][j] = mfma16h(af[i], bf[j], acc[i][j]);
    }

    #pragma unroll
    for (int i = 0; i < 4; ++i) {
        #pragma unroll
        for (int j = 0; j < 4; ++j) {
            int colIdx = n0 + wn + j * 16 + ln;
            float bs = bias[colIdx];
            #pragma unroll
            for (int r = 0; r < 4; ++r) {
                int row = m0 + wm + i * 16 + lq * 4 + r;
                C[(size_t)row * N + colIdx] = acc[i][j][r] + bs;
            }
        }
    }
}

// ------- normalize q,k -> f16; layout [BH][S][D] ----------------------------
__global__ __launch_bounds__(256)
void normalize_qk_f16(const float* __restrict__ qkv,
                      f16* __restrict__ qf, f16* __restrict__ kf)
{
    int w    = blockIdx.x * 4 + (threadIdx.x >> 6);
    int lane = threadIdx.x & 63;
    int n = w >> 4, h = w & 15;
    int b = n >> 11, s = n & 2047;
    const float* base = qkv + (size_t)n * 3 * HIDN + h * HD;
    float q = base[lane], k = base[HIDN + lane];
    float qs = q * q, ks = k * k;
    #pragma unroll
    for (int o = 32; o; o >>= 1) { qs += __shfl_xor(qs, o); ks += __shfl_xor(ks, o); }
    q *= 1.0f / fmaxf(sqrtf(qs), 1e-12f);
    k *= 1.0f / fmaxf(sqrtf(ks), 1e-12f);
    size_t idx = ((size_t)((b * NH + h) * SEQ + s)) * HD + lane;
    qf[idx] = (f16)q;
    kf[idx] = (f16)k;
}

// ------- V: bf16, transpose to [BH][D][S] -----------------------------------
__global__ __launch_bounds__(256)
void v_transpose(const float* __restrict__ qkv, unsigned short* __restrict__ vth)
{
    __shared__ float Ls[64][65];
    int bh = blockIdx.y, s0 = blockIdx.x * 64;
    int b = bh >> 4, h = bh & 15;
    int tid = threadIdx.x;
    #pragma unroll
    for (int i = 0; i < 4; ++i) {
        int idx = tid + i * 256;
        int row = idx >> 4, c4 = (idx & 15) * 4;
        float4 v = *(const float4*)&qkv[((size_t)(b * SEQ + s0 + row)) * 3 * HIDN
                                        + 2 * HIDN + h * HD + c4];
        Ls[row][c4+0] = v.x; Ls[row][c4+1] = v.y; Ls[row][c4+2] = v.z; Ls[row][c4+3] = v.w;
    }
    __syncthreads();
    int d = tid >> 2, sb = (tid & 3) * 16;
    unsigned short hi[16];
    #pragma unroll
    for (int j = 0; j < 16; ++j) hi[j] = f2bf(Ls[sb + j][d]);
    size_t o = ((size_t)bh * HD + d) * SEQ + s0 + sb;
    *(uint4*)&vth[o]     = *(uint4*)&hi[0];
    *(uint4*)&vth[o + 8] = *(uint4*)&hi[8];
}

// ------- col[bh,t] = (sum_s score(q_s . k_t))^-0.5, pipelined ---------------
__global__ __launch_bounds__(256)
void col_sum_f16(const f16* __restrict__ qf, const f16* __restrict__ kf,
                 float* __restrict__ col)
{
    int bh = blockIdx.y, t0 = blockIdx.x * 64;
    int tid = threadIdx.x, w = tid >> 6, lane = tid & 63, ln = lane & 15, lq = lane >> 4;
    int m0 = t0 + w * 16;
    const f16* qb = qf + (size_t)bh * SEQ * HD;
    size_t rowK = ((size_t)bh * SEQ + m0 + ln) * HD;
    f16x8 kf0 = ldfragh(kf + rowK + lq * 8), kf1 = ldfragh(kf + rowK + 32 + lq * 8);

    f16x8 qcur[4][2];
    #pragma unroll
    for (int nt = 0; nt < 4; ++nt) {
        const f16* p = qb + (size_t)(nt * 16 + ln) * HD + lq * 8;
        qcur[nt][0] = ldfragh(p); qcur[nt][1] = ldfragh(p + 32);
    }

    float cacc[4] = {0.f, 0.f, 0.f, 0.f};
    for (int st = 0; st < SEQ / 64; ++st) {
        int sn = (st + 1 < SEQ / 64) ? (st + 1) * 64 : 0;   // clamped prefetch
        f16x8 qnxt[4][2];
        #pragma unroll
        for (int nt = 0; nt < 4; ++nt) {
            const f16* p = qb + (size_t)(sn + nt * 16 + ln) * HD + lq * 8;
            qnxt[nt][0] = ldfragh(p); qnxt[nt][1] = ldfragh(p + 32);
        }
        f32x4 sacc[4];
        #pragma unroll
        for (int nt = 0; nt < 4; ++nt) {
            sacc[nt] = (f32x4){0.f, 0.f, 0.f, 0.f};
            sacc[nt] = mfma16h(kf0, qcur[nt][0], sacc[nt]);
            sacc[nt] = mfma16h(kf1, qcur[nt][1], sacc[nt]);
        }
        #pragma unroll
        for (int nt = 0; nt < 4; ++nt)
            #pragma unroll
            for (int r = 0; r < 4; ++r) cacc[r] += score_fast(sacc[nt][r]);
        #pragma unroll
        for (int nt = 0; nt < 4; ++nt) {
            qcur[nt][0] = qnxt[nt][0]; qcur[nt][1] = qnxt[nt][1];
        }
    }
    #pragma unroll
    for (int r = 0; r < 4; ++r) {
        float v = cacc[r];
        v += __shfl_xor(v, 1); v += __shfl_xor(v, 2);
        v += __shfl_xor(v, 4); v += __shfl_xor(v, 8);
        if (ln == 0) col[(size_t)bh * SEQ + m0 + lq * 4 + r] = 1.0f / sqrtf(v);
    }
}

// ------- fused scores -> W(bf16) -> W@V, K-prefetch pipelined, no barrier ---
#define WSTR 72
__global__ __launch_bounds__(256)
void attn_f16(const f16* __restrict__ qf, const f16* __restrict__ kf,
              const unsigned short* __restrict__ vth,
              const float* __restrict__ col, f16* __restrict__ ctx)
{
    __shared__ __align__(16) unsigned short Ws[4][16 * WSTR];
    int bh = blockIdx.y;
    int b = bh >> 4, h = bh & 15;
    int tid = threadIdx.x, w = tid >> 6, lane = tid & 63, ln = lane & 15, lq = lane >> 4;
    int m0 = blockIdx.x * 64 + w * 16;
    unsigned short* ws = Ws[w];

    const f16* kb = kf + (size_t)bh * SEQ * HD;
    const unsigned short* vb = vth + (size_t)bh * HD * SEQ;
    const float* cb = col + (size_t)bh * SEQ;

    size_t rowQ = ((size_t)bh * SEQ + m0 + ln) * HD;
    f16x8 qf0 = ldfragh(qf + rowQ + lq * 8), qf1 = ldfragh(qf + rowQ + 32 + lq * 8);

    f32x4 num[4];
    #pragma unroll
    for (int nt = 0; nt < 4; ++nt) num[nt] = (f32x4){0.f, 0.f, 0.f, 0.f};
    float dpart[4] = {0.f, 0.f, 0.f, 0.f};

    // prologue: K/col for tile 0
    f16x8 kcur[4][2]; float cl[4];
    #pragma unroll
    for (int nt = 0; nt < 4; ++nt) {
        const f16* p = kb + (size_t)(nt * 16 + ln) * HD + lq * 8;
        kcur[nt][0] = ldfragh(p); kcur[nt][1] = ldfragh(p + 32);
        cl[nt] = cb[nt * 16 + ln];
    }

    for (int tt = 0; tt < SEQ / 64; ++tt) {
        int t0 = tt * 64;
        int tn = (tt + 1 < SEQ / 64) ? (tt + 1) * 64 : 0;   // clamped prefetch
        // prefetch next K tile + col
        f16x8 knxt[4][2]; float cln[4];
        #pragma unroll
        for (int nt = 0; nt < 4; ++nt) {
            const f16* p = kb + (size_t)(tn + nt * 16 + ln) * HD + lq * 8;
            knxt[nt][0] = ldfragh(p); knxt[nt][1] = ldfragh(p + 32);
            cln[nt] = cb[tn + nt * 16 + ln];
        }
        // issue V loads early (consumed at end of iteration)
        bf16x8 vfr[4][2];
        #pragma unroll
        for (int nt = 0; nt < 4; ++nt) {
            const unsigned short* pv = vb + (size_t)(nt * 16 + ln) * SEQ + t0 + lq * 8;
            vfr[nt][0] = ldfrag(pv); vfr[nt][1] = ldfrag(pv + 32);
        }
        // QK^T from registers (prefetched last iter)
        f32x4 sacc[4];
        #pragma unroll
        for (int nt = 0; nt < 4; ++nt) {
            sacc[nt] = (f32x4){0.f, 0.f, 0.f, 0.f};
            sacc[nt] = mfma16h(qf0, kcur[nt][0], sacc[nt]);
            sacc[nt] = mfma16h(qf1, kcur[nt][1], sacc[nt]);
        }
        // score + col-scale -> Ws (bf16; values ~2^-50, below fp16 range)
        #pragma unroll
        for (int nt = 0; nt < 4; ++nt) {
            #pragma unroll
            for (int r = 0; r < 4; ++r) {
                float wv = score_fast(sacc[nt][r]) * cl[nt];
                unsigned short wb = f2bf(wv);
                dpart[r] += bf2f(wb);
                ws[(lq * 4 + r) * WSTR + nt * 16 + ln] = wb;
            }
        }
        // W in A-layout (per-wave LDS, no barrier), PV
        bf16x8 wa0 = ldfrag(ws + ln * WSTR + lq * 8);
        bf16x8 wa1 = ldfrag(ws + ln * WSTR + 32 + lq * 8);
        #pragma unroll
        for (int nt = 0; nt < 4; ++nt) {
            num[nt] = mfma16(wa0, vfr[nt][0], num[nt]);
            num[nt] = mfma16(wa1, vfr[nt][1], num[nt]);
        }
        // rotate prefetch
        #pragma unroll
        for (int nt = 0; nt < 4; ++nt) {
            kcur[nt][0] = knxt[nt][0]; kcur[nt][1] = knxt[nt][1];
            cl[nt] = cln[nt];
        }
    }

    #pragma unroll
    for (int r = 0; r < 4; ++r) {
        float v = dpart[r];
        v += __shfl_xor(v, 1); v += __shfl_xor(v, 2);
        v += __shfl_xor(v, 4); v += __shfl_xor(v, 8);
        dpart[r] = v;
    }
    #pragma unroll
    for (int r = 0; r < 4; ++r) {
        float inv = 1.0f / fmaxf(dpart[r], 1e-12f);
        int s = m0 + lq * 4 + r;
        #pragma unroll
        for (int nt = 0; nt < 4; ++nt)
            ctx[((size_t)(b * SEQ + s)) * HIDN + h * HD + nt * 16 + ln] =
                (f16)(num[nt][r] * inv);
    }
}

extern "C" void kernel_launch(void* const* d_in, const int* in_sizes, int n_in,
                              void* d_out, int out_size, void* d_ws, size_t ws_size,
                              hipStream_t stream) {
    const float* x      = (const float*)d_in[0];
    const float* qkv_w  = (const float*)d_in[1];
    const float* qkv_b  = (const float*)d_in[2];
    const float* out_w  = (const float*)d_in[3];
    const float* out_b  = (const float*)d_in[4];
    float* out = (float*)d_out;

    const size_t NTT = (size_t)BH * SEQ * HD;             // 4.19M
    float* qkv = (float*)d_ws;
    float* col = qkv + (size_t)ROWS * 3 * HIDN;
    f16* xh    = (f16*)(col + (size_t)BH * SEQ);
    f16* wqh   = xh + (size_t)ROWS * HIDN;
    f16* woh   = wqh + (size_t)3 * HIDN * HIDN;
    f16* ctxh  = woh + (size_t)HIDN * HIDN;
    f16* qfp   = ctxh + (size_t)ROWS * HIDN;
    f16* kfp   = qfp + NTT;
    unsigned short* vth = (unsigned short*)(kfp + NTT);

    conv_f16<<<ROWS*HIDN/2048, 256, 0, stream>>>(x, xh);
    conv_f16<<<3*HIDN*HIDN/2048, 256, 0, stream>>>(qkv_w, wqh);
    conv_f16<<<HIDN*HIDN/2048, 256, 0, stream>>>(out_w, woh);

    gemm_nt_f16<<<dim3(ROWS/128, 3*HIDN/128), 256, 0, stream>>>(
        xh, wqh, qkv_b, qkv, ROWS, 3*HIDN, HIDN);
    normalize_qk_f16<<<ROWS*NH/4, 256, 0, stream>>>(qkv, qfp, kfp);
    v_transpose<<<dim3(SEQ/64, BH), 256, 0, stream>>>(qkv, vth);
    col_sum_f16<<<dim3(SEQ/64, BH), 256, 0, stream>>>(qfp, kfp, col);
    attn_f16<<<dim3(SEQ/64, BH), 256, 0, stream>>>(qfp, kfp, vth, col, ctxh);
    gemm_nt_f16<<<dim3(ROWS/128, HIDN/128), 256, 0, stream>>>(
        ctxh, woh, out_b, out, ROWS, HIDN, HIDN);
}